// Round 1
// baseline (875.926 us; speedup 1.0000x reference)
//
#include <hip/hip_runtime.h>

// ---------------- problem constants ----------------
#define BATCH 16
#define SEQ   1024
#define EMBED 1280
#define NH    16
#define HD    80
#define HDP   96           // HD padded to 3*32 for MFMA K-steps
#define NQKV  3840
#define MTOK  (BATCH*SEQ)  // 16384
#define SCALE 0.11180339887498948f
#define LOG2E 1.4426950408889634f

typedef _Float16 half8 __attribute__((ext_vector_type(8)));
typedef _Float16 half4 __attribute__((ext_vector_type(4)));
typedef float floatx4 __attribute__((ext_vector_type(4)));

#define GLD_TO_LDS(gp, lp)                                                        \
  __builtin_amdgcn_global_load_lds(                                               \
      (const __attribute__((address_space(1))) void*)(gp),                        \
      (__attribute__((address_space(3))) void*)(lp), 16, 0, 0)

// ---------------- converts ----------------
__global__ void cvt_f32_to_f16(const float4* __restrict__ in, _Float16* __restrict__ out, int n4) {
  int i = blockIdx.x * blockDim.x + threadIdx.x;
  if (i < n4) {
    float4 v = in[i];
    half4 h;
    h[0] = (_Float16)v.x; h[1] = (_Float16)v.y; h[2] = (_Float16)v.z; h[3] = (_Float16)v.w;
    *(half4*)(out + (size_t)i * 4) = h;
  }
}

// in [K=1280 x N] fp32 row-major -> out [N x 1280] f16 (transposed)
template <int N>
__global__ void cvt_transpose_f16(const float* __restrict__ in, _Float16* __restrict__ out) {
  int idx = blockIdx.x * blockDim.x + threadIdx.x;
  if (idx < N * 1280) {
    int n = idx / 1280;
    int k = idx - n * 1280;
    out[idx] = (_Float16)in[(size_t)k * N + n];
  }
}

// ---------------- GEMM: A[M x 1280] f16 row-major, Bt[N x 1280] f16 row-major ----------------
// MODE 0: QKV epilogue (bias + scatter to q_pad/k_pad/v_t, f16)
// MODE 1: proj epilogue (bias + fp32 out [M x 1280])
template <int MODE>
__global__ __launch_bounds__(256, 2)
void gemm_kernel(const _Float16* __restrict__ A, const _Float16* __restrict__ Bt,
                 const float* __restrict__ bias,
                 _Float16* __restrict__ q_pad, _Float16* __restrict__ k_pad,
                 _Float16* __restrict__ v_t, float* __restrict__ outf) {
  __shared__ __align__(16) _Float16 sA[128 * 32];
  __shared__ __align__(16) _Float16 sB[128 * 32];
  const int K = 1280;
  const int tid = threadIdx.x;
  const int wave = tid >> 6;
  const int lane = tid & 63;
  const int quad = lane >> 4;
  const int r16 = lane & 15;
  const int wm = wave >> 1, wn = wave & 1;
  const int m0 = blockIdx.y * 128;
  const int n0 = blockIdx.x * 128;

  floatx4 acc[4][4] = {};

  // staging: 512 chunks of 16B per tile; chunk c -> row=c>>2, kchunk=c&3
  const int c_base = wave * 128 + lane;  // issues at c_base and c_base+64
  for (int k0 = 0; k0 < K; k0 += 32) {
    __syncthreads();
#pragma unroll
    for (int i = 0; i < 2; ++i) {
      int c = c_base + i * 64;
      int row = c >> 2, kc = c & 3;
      GLD_TO_LDS(A + (size_t)(m0 + row) * K + k0 + kc * 8, sA + (size_t)(wave * 2 + i) * 512);
      GLD_TO_LDS(Bt + (size_t)(n0 + row) * K + k0 + kc * 8, sB + (size_t)(wave * 2 + i) * 512);
    }
    __syncthreads();

    half8 af[4], bf[4];
#pragma unroll
    for (int mi = 0; mi < 4; ++mi)
      af[mi] = *(const half8*)(sA + (wm * 64 + mi * 16 + r16) * 32 + quad * 8);
#pragma unroll
    for (int ni = 0; ni < 4; ++ni)
      bf[ni] = *(const half8*)(sB + (wn * 64 + ni * 16 + r16) * 32 + quad * 8);
#pragma unroll
    for (int mi = 0; mi < 4; ++mi)
#pragma unroll
      for (int ni = 0; ni < 4; ++ni)
        acc[mi][ni] = __builtin_amdgcn_mfma_f32_16x16x32_f16(af[mi], bf[ni], acc[mi][ni], 0, 0, 0);
  }

  if (MODE == 1) {
#pragma unroll
    for (int mi = 0; mi < 4; ++mi)
#pragma unroll
      for (int ni = 0; ni < 4; ++ni) {
        int n = n0 + wn * 64 + ni * 16 + r16;
        float bv = bias[n];
#pragma unroll
        for (int r = 0; r < 4; ++r) {
          int m = m0 + wm * 64 + mi * 16 + quad * 4 + r;
          outf[(size_t)m * EMBED + n] = acc[mi][ni][r] + bv;
        }
      }
  } else {
#pragma unroll
    for (int mi = 0; mi < 4; ++mi)
#pragma unroll
      for (int ni = 0; ni < 4; ++ni) {
        int n = n0 + wn * 64 + ni * 16 + r16;
        float bv = bias[n];
        int which = n / 1280;
        int rem = n - which * 1280;
        int h = rem / 80;
        int d = rem - h * 80;
#pragma unroll
        for (int r = 0; r < 4; ++r) {
          int m = m0 + wm * 64 + mi * 16 + quad * 4 + r;
          int b = m >> 10, s = m & 1023;
          int bh = b * NH + h;
          _Float16 val = (_Float16)(acc[mi][ni][r] + bv);
          if (which == 0)      q_pad[((size_t)bh * SEQ + s) * HDP + d] = val;
          else if (which == 1) k_pad[((size_t)bh * SEQ + s) * HDP + d] = val;
          else                 v_t[((size_t)bh * HD + d) * SEQ + s] = val;
        }
      }
  }
}

// ---------------- flash attention ----------------
// grid: (BATCH*NH) * (SEQ/64) blocks, 256 thr. wave w owns q-rows [q0+w*16, +16).
__global__ __launch_bounds__(256, 2)
void attn_kernel(const _Float16* __restrict__ q_pad, const _Float16* __restrict__ k_pad,
                 const _Float16* __restrict__ v_t, _Float16* __restrict__ attn_out) {
  __shared__ __align__(16) _Float16 sK[64 * HDP];   // 12 KB
  __shared__ __align__(16) _Float16 sV[HD * 64];    // 10 KB
  __shared__ __align__(16) _Float16 sP[4][16 * 64]; // 8 KB

  const int tid = threadIdx.x;
  const int wave = tid >> 6, lane = tid & 63, quad = lane >> 4, r16 = lane & 15;
  const int bh = blockIdx.x >> 4;
  const int q0 = (blockIdx.x & 15) * 64;

  // Q fragments live in registers (A-layout: m=lane&15, k=quad*8+j)
  half8 qf[3];
  const _Float16* qbase = q_pad + ((size_t)bh * SEQ + q0 + wave * 16 + r16) * HDP;
#pragma unroll
  for (int kq = 0; kq < 3; ++kq) qf[kq] = *(const half8*)(qbase + kq * 32 + quad * 8);

  floatx4 o[5] = {};
  float mrow[4], lrow[4];
#pragma unroll
  for (int r = 0; r < 4; ++r) { mrow[r] = -1e30f; lrow[r] = 0.f; }

  for (int kt = 0; kt < 16; ++kt) {
    __syncthreads();
    {  // stage K tile: 64 rows x 96 halfs = 768 x 16B chunks
      const _Float16* kb = k_pad + ((size_t)bh * SEQ + kt * 64) * HDP;
#pragma unroll
      for (int i = 0; i < 3; ++i) {
        int c = tid + i * 256;
        int row = c / 12, col = c - row * 12;
        *(uint4*)(sK + row * HDP + col * 8) = *(const uint4*)(kb + (size_t)row * HDP + col * 8);
      }
      // stage V^T tile: 80 rows x 64 halfs = 640 x 16B chunks
      const _Float16* vb = v_t + (size_t)bh * HD * SEQ + kt * 64;
#pragma unroll
      for (int i = 0; i < 3; ++i) {
        int c = tid + i * 256;
        if (c < 640) {
          int row = c >> 3, col = c & 7;
          *(uint4*)(sV + row * 64 + col * 8) = *(const uint4*)(vb + (size_t)row * SEQ + col * 8);
        }
      }
    }
    __syncthreads();

    // S = Q K^T  (16 q x 64 k per wave)
    floatx4 sacc[4] = {};
#pragma unroll
    for (int ni = 0; ni < 4; ++ni)
#pragma unroll
      for (int kq = 0; kq < 3; ++kq) {
        half8 kf = *(const half8*)(sK + (ni * 16 + r16) * HDP + kq * 32 + quad * 8);
        sacc[ni] = __builtin_amdgcn_mfma_f32_16x16x32_f16(qf[kq], kf, sacc[ni], 0, 0, 0);
      }

    // online softmax per q-row (C-layout: row=quad*4+r, col=ni*16+r16)
    float p[4][4];
#pragma unroll
    for (int r = 0; r < 4; ++r) {
      float mx = -1e30f;
#pragma unroll
      for (int ni = 0; ni < 4; ++ni) {
        float sv = sacc[ni][r] * SCALE;
        p[ni][r] = sv;
        mx = fmaxf(mx, sv);
      }
#pragma unroll
      for (int off = 1; off < 16; off <<= 1) mx = fmaxf(mx, __shfl_xor(mx, off));
      float mnew = fmaxf(mrow[r], mx);
      float alpha = __builtin_amdgcn_exp2f((mrow[r] - mnew) * LOG2E);
      float sum = 0.f;
#pragma unroll
      for (int ni = 0; ni < 4; ++ni) {
        float pv = __builtin_amdgcn_exp2f((p[ni][r] - mnew) * LOG2E);
        p[ni][r] = pv;
        sum += pv;
      }
#pragma unroll
      for (int off = 1; off < 16; off <<= 1) sum += __shfl_xor(sum, off);
      lrow[r] = lrow[r] * alpha + sum;
      mrow[r] = mnew;
#pragma unroll
      for (int di = 0; di < 5; ++di) o[di][r] *= alpha;
    }

    // P: C-layout -> A-layout via per-wave LDS region (same-wave DS ops are in-order)
#pragma unroll
    for (int ni = 0; ni < 4; ++ni)
#pragma unroll
      for (int r = 0; r < 4; ++r)
        sP[wave][(quad * 4 + r) * 64 + ni * 16 + r16] = (_Float16)p[ni][r];

#pragma unroll
    for (int kp = 0; kp < 2; ++kp) {
      half8 pf = *(const half8*)(&sP[wave][r16 * 64 + kp * 32 + quad * 8]);
#pragma unroll
      for (int di = 0; di < 5; ++di) {
        half8 vf = *(const half8*)(sV + (di * 16 + r16) * 64 + kp * 32 + quad * 8);
        o[di] = __builtin_amdgcn_mfma_f32_16x16x32_f16(pf, vf, o[di], 0, 0, 0);
      }
    }
  }

  // epilogue: attn_out[b, s, h*80+d] f16
  const int b = bh >> 4, h = bh & 15;
#pragma unroll
  for (int r = 0; r < 4; ++r) {
    float inv = 1.0f / lrow[r];
    int tok = b * SEQ + q0 + wave * 16 + quad * 4 + r;
#pragma unroll
    for (int di = 0; di < 5; ++di) {
      int e = h * HD + di * 16 + r16;
      attn_out[(size_t)tok * EMBED + e] = (_Float16)(o[di][r] * inv);
    }
  }
}

// ---------------- launch ----------------
extern "C" void kernel_launch(void* const* d_in, const int* in_sizes, int n_in,
                              void* d_out, int out_size, void* d_ws, size_t ws_size,
                              hipStream_t stream) {
  const float* hidden = (const float*)d_in[0];
  const float* w_qkv  = (const float*)d_in[1];
  const float* b_qkv  = (const float*)d_in[2];
  const float* w_proj = (const float*)d_in[3];
  const float* b_proj = (const float*)d_in[4];
  float* out = (float*)d_out;

  char* ws = (char*)d_ws;
  size_t off = 0;
  _Float16* hidden_h = (_Float16*)(ws + off); off += (size_t)MTOK * EMBED * 2;   // 41.9 MB
  _Float16* wqkv_t   = (_Float16*)(ws + off); off += (size_t)NQKV * EMBED * 2;   //  9.8 MB
  _Float16* wproj_t  = (_Float16*)(ws + off); off += (size_t)EMBED * EMBED * 2;  //  3.3 MB
  _Float16* q_pad    = (_Float16*)(ws + off); off += (size_t)BATCH * NH * SEQ * HDP * 2; // 50.3 MB
  _Float16* k_pad    = (_Float16*)(ws + off); off += (size_t)BATCH * NH * SEQ * HDP * 2; // 50.3 MB
  _Float16* v_t      = (_Float16*)(ws + off); off += (size_t)BATCH * NH * HD * SEQ * 2;  // 41.9 MB
  _Float16* attn_out = hidden_h;  // alias: hidden_h consumed before attention writes

  // zero the d=80..95 pad (product with pad must be 0)
  hipMemsetAsync(q_pad, 0, (size_t)BATCH * NH * SEQ * HDP * 2, stream);
  hipMemsetAsync(k_pad, 0, (size_t)BATCH * NH * SEQ * HDP * 2, stream);

  {
    int n4 = MTOK * EMBED / 4;
    cvt_f32_to_f16<<<(n4 + 255) / 256, 256, 0, stream>>>((const float4*)hidden, hidden_h, n4);
  }
  cvt_transpose_f16<NQKV><<<(NQKV * EMBED + 255) / 256, 256, 0, stream>>>(w_qkv, wqkv_t);
  cvt_transpose_f16<EMBED><<<(EMBED * EMBED + 255) / 256, 256, 0, stream>>>(w_proj, wproj_t);

  gemm_kernel<0><<<dim3(NQKV / 128, MTOK / 128), 256, 0, stream>>>(
      hidden_h, wqkv_t, b_qkv, q_pad, k_pad, v_t, nullptr);

  attn_kernel<<<BATCH * NH * (SEQ / 64), 256, 0, stream>>>(q_pad, k_pad, v_t, attn_out);

  gemm_kernel<1><<<dim3(EMBED / 128, MTOK / 128), 256, 0, stream>>>(
      attn_out, wproj_t, b_proj, nullptr, nullptr, nullptr, out);
}

// Round 2
// 842.918 us; speedup vs baseline: 1.0392x; 1.0392x over previous
//
#include <hip/hip_runtime.h>

// ---------------- problem constants ----------------
#define BATCH 16
#define SEQ   1024
#define EMBED 1280
#define NH    16
#define HD    80
#define HDP   96           // HD padded to 3*32 for MFMA K-steps
#define NQKV  3840
#define MTOK  (BATCH*SEQ)  // 16384
#define SCALE 0.11180339887498948f
#define LOG2E 1.4426950408889634f

// LDS strides padded to kill bank conflicts (keep 16B alignment for b128 reads)
#define SK_STRIDE 104      // 52 dwords, %32=20 -> 2 lanes/bank (free)
#define SV_STRIDE 72       // 36 dwords, %32=4  -> 2 lanes/bank (free)
#define SP_STRIDE 72

typedef _Float16 half8 __attribute__((ext_vector_type(8)));
typedef _Float16 half4 __attribute__((ext_vector_type(4)));
typedef float floatx4 __attribute__((ext_vector_type(4)));

#define GLD_TO_LDS(gp, lp)                                                        \
  __builtin_amdgcn_global_load_lds(                                               \
      (const __attribute__((address_space(1))) void*)(gp),                        \
      (__attribute__((address_space(3))) void*)(lp), 16, 0, 0)

// ---------------- converts ----------------
__global__ void cvt_f32_to_f16(const float4* __restrict__ in, _Float16* __restrict__ out, int n4) {
  int i = blockIdx.x * blockDim.x + threadIdx.x;
  if (i < n4) {
    float4 v = in[i];
    half4 h;
    h[0] = (_Float16)v.x; h[1] = (_Float16)v.y; h[2] = (_Float16)v.z; h[3] = (_Float16)v.w;
    *(half4*)(out + (size_t)i * 4) = h;
  }
}

// in [K=1280 x N] fp32 row-major -> out [N x 1280] f16 (transposed)
template <int N>
__global__ void cvt_transpose_f16(const float* __restrict__ in, _Float16* __restrict__ out) {
  int idx = blockIdx.x * blockDim.x + threadIdx.x;
  if (idx < N * 1280) {
    int n = idx / 1280;
    int k = idx - n * 1280;
    out[idx] = (_Float16)in[(size_t)k * N + n];
  }
}

// ---------------- GEMM: A[M x 1280] f16 row-major, Bt[N x 1280] f16 row-major ----------------
// MODE 0: QKV epilogue (bias + scatter to q_pad/k_pad/v_t, f16)
// MODE 1: proj epilogue (bias + fp32 out [M x 1280])
template <int MODE>
__global__ __launch_bounds__(256, 2)
void gemm_kernel(const _Float16* __restrict__ A, const _Float16* __restrict__ Bt,
                 const float* __restrict__ bias,
                 _Float16* __restrict__ q_pad, _Float16* __restrict__ k_pad,
                 _Float16* __restrict__ v_t, float* __restrict__ outf) {
  __shared__ __align__(16) _Float16 sA[128 * 32];
  __shared__ __align__(16) _Float16 sB[128 * 32];
  const int K = 1280;
  const int tid = threadIdx.x;
  const int wave = tid >> 6;
  const int lane = tid & 63;
  const int quad = lane >> 4;
  const int r16 = lane & 15;
  const int wm = wave >> 1, wn = wave & 1;
  const int m0 = blockIdx.y * 128;
  const int n0 = blockIdx.x * 128;

  floatx4 acc[4][4] = {};

  // staging: 512 chunks of 16B per tile; chunk c -> row=c>>2, kchunk=c&3
  const int c_base = wave * 128 + lane;  // issues at c_base and c_base+64
  for (int k0 = 0; k0 < K; k0 += 32) {
    __syncthreads();
#pragma unroll
    for (int i = 0; i < 2; ++i) {
      int c = c_base + i * 64;
      int row = c >> 2, kc = c & 3;
      GLD_TO_LDS(A + (size_t)(m0 + row) * K + k0 + kc * 8, sA + (size_t)(wave * 2 + i) * 512);
      GLD_TO_LDS(Bt + (size_t)(n0 + row) * K + k0 + kc * 8, sB + (size_t)(wave * 2 + i) * 512);
    }
    __syncthreads();

    half8 af[4], bf[4];
#pragma unroll
    for (int mi = 0; mi < 4; ++mi)
      af[mi] = *(const half8*)(sA + (wm * 64 + mi * 16 + r16) * 32 + quad * 8);
#pragma unroll
    for (int ni = 0; ni < 4; ++ni)
      bf[ni] = *(const half8*)(sB + (wn * 64 + ni * 16 + r16) * 32 + quad * 8);
#pragma unroll
    for (int mi = 0; mi < 4; ++mi)
#pragma unroll
      for (int ni = 0; ni < 4; ++ni)
        acc[mi][ni] = __builtin_amdgcn_mfma_f32_16x16x32_f16(af[mi], bf[ni], acc[mi][ni], 0, 0, 0);
  }

  if (MODE == 1) {
#pragma unroll
    for (int mi = 0; mi < 4; ++mi)
#pragma unroll
      for (int ni = 0; ni < 4; ++ni) {
        int n = n0 + wn * 64 + ni * 16 + r16;
        float bv = bias[n];
#pragma unroll
        for (int r = 0; r < 4; ++r) {
          int m = m0 + wm * 64 + mi * 16 + quad * 4 + r;
          outf[(size_t)m * EMBED + n] = acc[mi][ni][r] + bv;
        }
      }
  } else {
#pragma unroll
    for (int mi = 0; mi < 4; ++mi)
#pragma unroll
      for (int ni = 0; ni < 4; ++ni) {
        int n = n0 + wn * 64 + ni * 16 + r16;
        float bv = bias[n];
        int which = n / 1280;
        int rem = n - which * 1280;
        int h = rem / 80;
        int d = rem - h * 80;
#pragma unroll
        for (int r = 0; r < 4; ++r) {
          int m = m0 + wm * 64 + mi * 16 + quad * 4 + r;
          int b = m >> 10, s = m & 1023;
          int bh = b * NH + h;
          _Float16 val = (_Float16)(acc[mi][ni][r] + bv);
          if (which == 0)      q_pad[((size_t)bh * SEQ + s) * HDP + d] = val;
          else if (which == 1) k_pad[((size_t)bh * SEQ + s) * HDP + d] = val;
          else                 v_t[((size_t)bh * HD + d) * SEQ + s] = val;
        }
      }
  }
}

// ---------------- flash attention ----------------
// grid: (BATCH*NH) * (SEQ/64) blocks, 256 thr. wave w owns q-rows [q0+w*16, +16).
__global__ __launch_bounds__(256, 2)
void attn_kernel(const _Float16* __restrict__ q_pad, const _Float16* __restrict__ k_pad,
                 const _Float16* __restrict__ v_t, _Float16* __restrict__ attn_out) {
  __shared__ __align__(16) _Float16 sK[64 * SK_STRIDE];      // 13.3 KB
  __shared__ __align__(16) _Float16 sV[HD * SV_STRIDE];      // 11.5 KB
  __shared__ __align__(16) _Float16 sP[4][16 * SP_STRIDE];   //  9.2 KB

  const int tid = threadIdx.x;
  const int wave = tid >> 6, lane = tid & 63, quad = lane >> 4, r16 = lane & 15;
  const int bh = blockIdx.x >> 4;
  const int q0 = (blockIdx.x & 15) * 64;

  // Q fragments live in registers (A-layout: m=lane&15, k=quad*8+j), pre-scaled
  half8 qf[3];
  const _Float16* qbase = q_pad + ((size_t)bh * SEQ + q0 + wave * 16 + r16) * HDP;
#pragma unroll
  for (int kq = 0; kq < 3; ++kq) {
    half8 q = *(const half8*)(qbase + kq * 32 + quad * 8);
#pragma unroll
    for (int j = 0; j < 8; ++j) q[j] = q[j] * (_Float16)SCALE;
    qf[kq] = q;
  }

  floatx4 o[5] = {};
  float mrow[4], lrow[4];
#pragma unroll
  for (int r = 0; r < 4; ++r) { mrow[r] = -1e30f; lrow[r] = 0.f; }

  for (int kt = 0; kt < 16; ++kt) {
    __syncthreads();
    {  // stage K tile: 64 rows x 96 halfs = 768 x 16B chunks (stride 104)
      const _Float16* kb = k_pad + ((size_t)bh * SEQ + kt * 64) * HDP;
#pragma unroll
      for (int i = 0; i < 3; ++i) {
        int c = tid + i * 256;
        int row = c / 12, col = c - row * 12;
        *(uint4*)(sK + row * SK_STRIDE + col * 8) = *(const uint4*)(kb + (size_t)row * HDP + col * 8);
      }
      // stage V^T tile: 80 rows x 64 halfs = 640 x 16B chunks (stride 72)
      const _Float16* vb = v_t + (size_t)bh * HD * SEQ + kt * 64;
#pragma unroll
      for (int i = 0; i < 3; ++i) {
        int c = tid + i * 256;
        if (c < 640) {
          int row = c >> 3, col = c & 7;
          *(uint4*)(sV + row * SV_STRIDE + col * 8) = *(const uint4*)(vb + (size_t)row * SEQ + col * 8);
        }
      }
    }
    __syncthreads();

    // S = Q K^T  (16 q x 64 k per wave); SCALE pre-folded into Q
    floatx4 sacc[4] = {};
#pragma unroll
    for (int ni = 0; ni < 4; ++ni)
#pragma unroll
      for (int kq = 0; kq < 3; ++kq) {
        half8 kf = *(const half8*)(sK + (ni * 16 + r16) * SK_STRIDE + kq * 32 + quad * 8);
        sacc[ni] = __builtin_amdgcn_mfma_f32_16x16x32_f16(qf[kq], kf, sacc[ni], 0, 0, 0);
      }

    // online softmax per q-row (C-layout: row=quad*4+r, col=ni*16+r16)
    float p[4][4];
#pragma unroll
    for (int r = 0; r < 4; ++r) {
      float mx = -1e30f;
#pragma unroll
      for (int ni = 0; ni < 4; ++ni) {
        float sv = sacc[ni][r];
        p[ni][r] = sv;
        mx = fmaxf(mx, sv);
      }
#pragma unroll
      for (int off = 1; off < 16; off <<= 1) mx = fmaxf(mx, __shfl_xor(mx, off));
      float mnew = fmaxf(mrow[r], mx);
      float alpha = __builtin_amdgcn_exp2f((mrow[r] - mnew) * LOG2E);
      float sum = 0.f;
#pragma unroll
      for (int ni = 0; ni < 4; ++ni) {
        float pv = __builtin_amdgcn_exp2f((p[ni][r] - mnew) * LOG2E);
        p[ni][r] = pv;
        sum += pv;
      }
#pragma unroll
      for (int off = 1; off < 16; off <<= 1) sum += __shfl_xor(sum, off);
      lrow[r] = lrow[r] * alpha + sum;
      mrow[r] = mnew;
#pragma unroll
      for (int di = 0; di < 5; ++di) o[di][r] *= alpha;
    }

    // P: C-layout -> A-layout via per-wave LDS region (same-wave DS ops are in-order)
#pragma unroll
    for (int ni = 0; ni < 4; ++ni)
#pragma unroll
      for (int r = 0; r < 4; ++r)
        sP[wave][(quad * 4 + r) * SP_STRIDE + ni * 16 + r16] = (_Float16)p[ni][r];

#pragma unroll
    for (int kp = 0; kp < 2; ++kp) {
      half8 pf = *(const half8*)(&sP[wave][r16 * SP_STRIDE + kp * 32 + quad * 8]);
#pragma unroll
      for (int di = 0; di < 5; ++di) {
        half8 vf = *(const half8*)(sV + (di * 16 + r16) * SV_STRIDE + kp * 32 + quad * 8);
        o[di] = __builtin_amdgcn_mfma_f32_16x16x32_f16(pf, vf, o[di], 0, 0, 0);
      }
    }
  }

  // epilogue: attn_out[b, s, h*80+d] f16
  const int b = bh >> 4, h = bh & 15;
#pragma unroll
  for (int r = 0; r < 4; ++r) {
    float inv = 1.0f / lrow[r];
    int tok = b * SEQ + q0 + wave * 16 + quad * 4 + r;
#pragma unroll
    for (int di = 0; di < 5; ++di) {
      int e = h * HD + di * 16 + r16;
      attn_out[(size_t)tok * EMBED + e] = (_Float16)(o[di][r] * inv);
    }
  }
}

// ---------------- launch ----------------
extern "C" void kernel_launch(void* const* d_in, const int* in_sizes, int n_in,
                              void* d_out, int out_size, void* d_ws, size_t ws_size,
                              hipStream_t stream) {
  const float* hidden = (const float*)d_in[0];
  const float* w_qkv  = (const float*)d_in[1];
  const float* b_qkv  = (const float*)d_in[2];
  const float* w_proj = (const float*)d_in[3];
  const float* b_proj = (const float*)d_in[4];
  float* out = (float*)d_out;

  char* ws = (char*)d_ws;
  size_t off = 0;
  _Float16* hidden_h = (_Float16*)(ws + off); off += (size_t)MTOK * EMBED * 2;   // 41.9 MB
  _Float16* wqkv_t   = (_Float16*)(ws + off); off += (size_t)NQKV * EMBED * 2;   //  9.8 MB
  _Float16* wproj_t  = (_Float16*)(ws + off); off += (size_t)EMBED * EMBED * 2;  //  3.3 MB
  _Float16* q_pad    = (_Float16*)(ws + off); off += (size_t)BATCH * NH * SEQ * HDP * 2; // 50.3 MB
  _Float16* k_pad    = (_Float16*)(ws + off); off += (size_t)BATCH * NH * SEQ * HDP * 2; // 50.3 MB
  _Float16* v_t      = (_Float16*)(ws + off); off += (size_t)BATCH * NH * HD * SEQ * 2;  // 41.9 MB
  _Float16* attn_out = hidden_h;  // alias: hidden_h consumed before attention writes

  // zero the d=80..95 pad (product with pad must be 0)
  hipMemsetAsync(q_pad, 0, (size_t)BATCH * NH * SEQ * HDP * 2, stream);
  hipMemsetAsync(k_pad, 0, (size_t)BATCH * NH * SEQ * HDP * 2, stream);

  {
    int n4 = MTOK * EMBED / 4;
    cvt_f32_to_f16<<<(n4 + 255) / 256, 256, 0, stream>>>((const float4*)hidden, hidden_h, n4);
  }
  cvt_transpose_f16<NQKV><<<(NQKV * EMBED + 255) / 256, 256, 0, stream>>>(w_qkv, wqkv_t);
  cvt_transpose_f16<EMBED><<<(EMBED * EMBED + 255) / 256, 256, 0, stream>>>(w_proj, wproj_t);

  gemm_kernel<0><<<dim3(NQKV / 128, MTOK / 128), 256, 0, stream>>>(
      hidden_h, wqkv_t, b_qkv, q_pad, k_pad, v_t, nullptr);

  attn_kernel<<<BATCH * NH * (SEQ / 64), 256, 0, stream>>>(q_pad, k_pad, v_t, attn_out);

  gemm_kernel<1><<<dim3(EMBED / 128, MTOK / 128), 256, 0, stream>>>(
      attn_out, wproj_t, b_proj, nullptr, nullptr, nullptr, out);
}

// Round 3
// 775.699 us; speedup vs baseline: 1.1292x; 1.0867x over previous
//
#include <hip/hip_runtime.h>

// ---------------- problem constants ----------------
#define BATCH 16
#define SEQ   1024
#define EMBED 1280
#define NH    16
#define HD    80
#define HDP   96           // HD padded to 3*32 for MFMA K-steps
#define NQKV  3840
#define MTOK  (BATCH*SEQ)  // 16384
#define SCALE 0.11180339887498948f
#define LOG2E 1.4426950408889634f

// LDS strides padded to kill bank conflicts (keep 16B alignment for b128 reads)
#define SK_STRIDE 104      // 52 dwords, %32=20 -> 2 lanes/bank (free)
#define SV_STRIDE 72       // 36 dwords, %32=4  -> 2 lanes/bank (free)
#define SP_STRIDE 72

typedef _Float16 half8 __attribute__((ext_vector_type(8)));
typedef _Float16 half4 __attribute__((ext_vector_type(4)));
typedef float floatx4 __attribute__((ext_vector_type(4)));

#define GLD_TO_LDS(gp, lp)                                                        \
  __builtin_amdgcn_global_load_lds(                                               \
      (const __attribute__((address_space(1))) void*)(gp),                        \
      (__attribute__((address_space(3))) void*)(lp), 16, 0, 0)

// ---------------- converts ----------------
__global__ void cvt_f32_to_f16(const float4* __restrict__ in, _Float16* __restrict__ out, int n4) {
  int i = blockIdx.x * blockDim.x + threadIdx.x;
  if (i < n4) {
    float4 v = in[i];
    half4 h;
    h[0] = (_Float16)v.x; h[1] = (_Float16)v.y; h[2] = (_Float16)v.z; h[3] = (_Float16)v.w;
    *(half4*)(out + (size_t)i * 4) = h;
  }
}

// in [K=1280 x N] fp32 row-major -> out [N x 1280] f16 (transposed)
template <int N>
__global__ void cvt_transpose_f16(const float* __restrict__ in, _Float16* __restrict__ out) {
  int idx = blockIdx.x * blockDim.x + threadIdx.x;
  if (idx < N * 1280) {
    int n = idx / 1280;
    int k = idx - n * 1280;
    out[idx] = (_Float16)in[(size_t)k * N + n];
  }
}

// ---------------- GEMM: A[M x 1280] f16 row-major, Bt[N x 1280] f16 row-major ----------------
// MODE 0: QKV epilogue (bias + scatter to q_pad/k_pad/v_t, f16), NT=30
// MODE 1: proj epilogue (bias + fp32 out [M x 1280]), NT=10
// 1-D grid of 128*NT blocks; XCD-aware swizzle (pid%8 -> contiguous m-strip).
template <int MODE, int NT>
__global__ __launch_bounds__(256, 2)
void gemm_kernel(const _Float16* __restrict__ A, const _Float16* __restrict__ Bt,
                 const float* __restrict__ bias,
                 _Float16* __restrict__ q_pad, _Float16* __restrict__ k_pad,
                 _Float16* __restrict__ v_t, float* __restrict__ outf) {
  __shared__ __align__(16) _Float16 sA[2][128 * 32];
  __shared__ __align__(16) _Float16 sB[2][128 * 32];
  const int K = 1280;
  const int tid = threadIdx.x;
  const int wave = tid >> 6;
  const int lane = tid & 63;
  const int quad = lane >> 4;
  const int r16 = lane & 15;
  const int wm = wave >> 1, wn = wave & 1;

  // swizzle: per-XCD contiguous 16-m-tile strip, traversed in 8m x NT panels (m fastest)
  const int pid = blockIdx.x;
  const int xcd = pid & 7;
  const int local = pid >> 3;               // [0, 16*NT)
  const int panel = local / (8 * NT);       // {0,1}
  const int rr = local - panel * (8 * NT);
  const int pm = rr & 7;
  const int pn = rr >> 3;                   // [0, NT)
  const int m0 = (xcd * 16 + panel * 8 + pm) * 128;
  const int n0 = pn * 128;

  floatx4 acc[4][4] = {};

  // staging: 512 chunks of 16B per tile; chunk c -> row=c>>2, kchunk=c&3
  const int c_base = wave * 128 + lane;  // issues at c_base and c_base+64

#define ISSUE(k0, buf)                                                              \
  do {                                                                              \
    _Pragma("unroll")                                                               \
    for (int i = 0; i < 2; ++i) {                                                   \
      int c = c_base + i * 64;                                                      \
      int row = c >> 2, kc = c & 3;                                                 \
      GLD_TO_LDS(A + (size_t)(m0 + row) * K + (k0) + kc * 8,                        \
                 &sA[buf][(wave * 2 + i) * 512]);                                   \
      GLD_TO_LDS(Bt + (size_t)(n0 + row) * K + (k0) + kc * 8,                       \
                 &sB[buf][(wave * 2 + i) * 512]);                                   \
    }                                                                               \
  } while (0)

  ISSUE(0, 0);
  for (int kt = 0; kt < 40; ++kt) {
    __syncthreads();  // vmcnt(0) drain: tile kt resident in buf kt&1; buf kt+1&1 fully consumed
    if (kt + 1 < 40) ISSUE((kt + 1) * 32, (kt + 1) & 1);
    const _Float16* pA = sA[kt & 1];
    const _Float16* pB = sB[kt & 1];

    half8 af[4], bf[4];
#pragma unroll
    for (int mi = 0; mi < 4; ++mi)
      af[mi] = *(const half8*)(pA + (wm * 64 + mi * 16 + r16) * 32 + quad * 8);
#pragma unroll
    for (int ni = 0; ni < 4; ++ni)
      bf[ni] = *(const half8*)(pB + (wn * 64 + ni * 16 + r16) * 32 + quad * 8);
#pragma unroll
    for (int mi = 0; mi < 4; ++mi)
#pragma unroll
      for (int ni = 0; ni < 4; ++ni)
        acc[mi][ni] = __builtin_amdgcn_mfma_f32_16x16x32_f16(af[mi], bf[ni], acc[mi][ni], 0, 0, 0);
  }

  if (MODE == 1) {
#pragma unroll
    for (int mi = 0; mi < 4; ++mi)
#pragma unroll
      for (int ni = 0; ni < 4; ++ni) {
        int n = n0 + wn * 64 + ni * 16 + r16;
        float bv = bias[n];
#pragma unroll
        for (int r = 0; r < 4; ++r) {
          int m = m0 + wm * 64 + mi * 16 + quad * 4 + r;
          outf[(size_t)m * EMBED + n] = acc[mi][ni][r] + bv;
        }
      }
  } else {
#pragma unroll
    for (int mi = 0; mi < 4; ++mi)
#pragma unroll
      for (int ni = 0; ni < 4; ++ni) {
        int n = n0 + wn * 64 + ni * 16 + r16;
        float bv = bias[n];
        int which = n / 1280;
        int rem = n - which * 1280;
        int h = rem / 80;
        int d = rem - h * 80;
#pragma unroll
        for (int r = 0; r < 4; ++r) {
          int m = m0 + wm * 64 + mi * 16 + quad * 4 + r;
          int b = m >> 10, s = m & 1023;
          int bh = b * NH + h;
          _Float16 val = (_Float16)(acc[mi][ni][r] + bv);
          if (which == 0)      q_pad[((size_t)bh * SEQ + s) * HDP + d] = val;
          else if (which == 1) k_pad[((size_t)bh * SEQ + s) * HDP + d] = val;
          else                 v_t[((size_t)bh * HD + d) * SEQ + s] = val;
        }
      }
  }
}

// ---------------- flash attention ----------------
// grid: (BATCH*NH) * (SEQ/64) blocks, 256 thr. wave w owns q-rows [q0+w*16, +16).
__global__ __launch_bounds__(256, 2)
void attn_kernel(const _Float16* __restrict__ q_pad, const _Float16* __restrict__ k_pad,
                 const _Float16* __restrict__ v_t, _Float16* __restrict__ attn_out) {
  __shared__ __align__(16) _Float16 sK[64 * SK_STRIDE];      // 13.3 KB
  __shared__ __align__(16) _Float16 sV[HD * SV_STRIDE];      // 11.5 KB
  __shared__ __align__(16) _Float16 sP[4][16 * SP_STRIDE];   //  9.2 KB

  const int tid = threadIdx.x;
  const int wave = tid >> 6, lane = tid & 63, quad = lane >> 4, r16 = lane & 15;
  const int bh = blockIdx.x >> 4;
  const int q0 = (blockIdx.x & 15) * 64;

  // Q fragments live in registers (A-layout: m=lane&15, k=quad*8+j), pre-scaled
  half8 qf[3];
  const _Float16* qbase = q_pad + ((size_t)bh * SEQ + q0 + wave * 16 + r16) * HDP;
#pragma unroll
  for (int kq = 0; kq < 3; ++kq) {
    half8 q = *(const half8*)(qbase + kq * 32 + quad * 8);
#pragma unroll
    for (int j = 0; j < 8; ++j) q[j] = q[j] * (_Float16)SCALE;
    qf[kq] = q;
  }

  floatx4 o[5] = {};
  float mrow[4], lrow[4];
#pragma unroll
  for (int r = 0; r < 4; ++r) { mrow[r] = -1e30f; lrow[r] = 0.f; }

  for (int kt = 0; kt < 16; ++kt) {
    __syncthreads();
    {  // stage K tile: 64 rows x 96 halfs = 768 x 16B chunks (stride 104)
      const _Float16* kb = k_pad + ((size_t)bh * SEQ + kt * 64) * HDP;
#pragma unroll
      for (int i = 0; i < 3; ++i) {
        int c = tid + i * 256;
        int row = c / 12, col = c - row * 12;
        *(uint4*)(sK + row * SK_STRIDE + col * 8) = *(const uint4*)(kb + (size_t)row * HDP + col * 8);
      }
      // stage V^T tile: 80 rows x 64 halfs = 640 x 16B chunks (stride 72)
      const _Float16* vb = v_t + (size_t)bh * HD * SEQ + kt * 64;
#pragma unroll
      for (int i = 0; i < 3; ++i) {
        int c = tid + i * 256;
        if (c < 640) {
          int row = c >> 3, col = c & 7;
          *(uint4*)(sV + row * SV_STRIDE + col * 8) = *(const uint4*)(vb + (size_t)row * SEQ + col * 8);
        }
      }
    }
    __syncthreads();

    // S = Q K^T  (16 q x 64 k per wave); SCALE pre-folded into Q
    floatx4 sacc[4] = {};
#pragma unroll
    for (int ni = 0; ni < 4; ++ni)
#pragma unroll
      for (int kq = 0; kq < 3; ++kq) {
        half8 kf = *(const half8*)(sK + (ni * 16 + r16) * SK_STRIDE + kq * 32 + quad * 8);
        sacc[ni] = __builtin_amdgcn_mfma_f32_16x16x32_f16(qf[kq], kf, sacc[ni], 0, 0, 0);
      }

    // online softmax per q-row (C-layout: row=quad*4+r, col=ni*16+r16)
    float p[4][4];
#pragma unroll
    for (int r = 0; r < 4; ++r) {
      float mx = -1e30f;
#pragma unroll
      for (int ni = 0; ni < 4; ++ni) {
        float sv = sacc[ni][r];
        p[ni][r] = sv;
        mx = fmaxf(mx, sv);
      }
#pragma unroll
      for (int off = 1; off < 16; off <<= 1) mx = fmaxf(mx, __shfl_xor(mx, off));
      float mnew = fmaxf(mrow[r], mx);
      float alpha = __builtin_amdgcn_exp2f((mrow[r] - mnew) * LOG2E);
      float sum = 0.f;
#pragma unroll
      for (int ni = 0; ni < 4; ++ni) {
        float pv = __builtin_amdgcn_exp2f((p[ni][r] - mnew) * LOG2E);
        p[ni][r] = pv;
        sum += pv;
      }
#pragma unroll
      for (int off = 1; off < 16; off <<= 1) sum += __shfl_xor(sum, off);
      lrow[r] = lrow[r] * alpha + sum;
      mrow[r] = mnew;
#pragma unroll
      for (int di = 0; di < 5; ++di) o[di][r] *= alpha;
    }

    // P: C-layout -> A-layout via per-wave LDS region (same-wave DS ops are in-order)
#pragma unroll
    for (int ni = 0; ni < 4; ++ni)
#pragma unroll
      for (int r = 0; r < 4; ++r)
        sP[wave][(quad * 4 + r) * SP_STRIDE + ni * 16 + r16] = (_Float16)p[ni][r];

#pragma unroll
    for (int kp = 0; kp < 2; ++kp) {
      half8 pf = *(const half8*)(&sP[wave][r16 * SP_STRIDE + kp * 32 + quad * 8]);
#pragma unroll
      for (int di = 0; di < 5; ++di) {
        half8 vf = *(const half8*)(sV + (di * 16 + r16) * SV_STRIDE + kp * 32 + quad * 8);
        o[di] = __builtin_amdgcn_mfma_f32_16x16x32_f16(pf, vf, o[di], 0, 0, 0);
      }
    }
  }

  // epilogue: attn_out[b, s, h*80+d] f16
  const int b = bh >> 4, h = bh & 15;
#pragma unroll
  for (int r = 0; r < 4; ++r) {
    float inv = 1.0f / lrow[r];
    int tok = b * SEQ + q0 + wave * 16 + quad * 4 + r;
#pragma unroll
    for (int di = 0; di < 5; ++di) {
      int e = h * HD + di * 16 + r16;
      attn_out[(size_t)tok * EMBED + e] = (_Float16)(o[di][r] * inv);
    }
  }
}

// ---------------- launch ----------------
extern "C" void kernel_launch(void* const* d_in, const int* in_sizes, int n_in,
                              void* d_out, int out_size, void* d_ws, size_t ws_size,
                              hipStream_t stream) {
  const float* hidden = (const float*)d_in[0];
  const float* w_qkv  = (const float*)d_in[1];
  const float* b_qkv  = (const float*)d_in[2];
  const float* w_proj = (const float*)d_in[3];
  const float* b_proj = (const float*)d_in[4];
  float* out = (float*)d_out;

  char* ws = (char*)d_ws;
  size_t off = 0;
  _Float16* hidden_h = (_Float16*)(ws + off); off += (size_t)MTOK * EMBED * 2;   // 41.9 MB
  _Float16* wqkv_t   = (_Float16*)(ws + off); off += (size_t)NQKV * EMBED * 2;   //  9.8 MB
  _Float16* wproj_t  = (_Float16*)(ws + off); off += (size_t)EMBED * EMBED * 2;  //  3.3 MB
  _Float16* q_pad    = (_Float16*)(ws + off); off += (size_t)BATCH * NH * SEQ * HDP * 2; // 50.3 MB
  _Float16* k_pad    = (_Float16*)(ws + off); off += (size_t)BATCH * NH * SEQ * HDP * 2; // 50.3 MB
  _Float16* v_t      = (_Float16*)(ws + off); off += (size_t)BATCH * NH * HD * SEQ * 2;  // 41.9 MB
  _Float16* attn_out = hidden_h;  // alias: hidden_h consumed before attention writes

  // zero the d=80..95 pad (product with pad must be 0)
  hipMemsetAsync(q_pad, 0, (size_t)BATCH * NH * SEQ * HDP * 2, stream);
  hipMemsetAsync(k_pad, 0, (size_t)BATCH * NH * SEQ * HDP * 2, stream);

  {
    int n4 = MTOK * EMBED / 4;
    cvt_f32_to_f16<<<(n4 + 255) / 256, 256, 0, stream>>>((const float4*)hidden, hidden_h, n4);
  }
  cvt_transpose_f16<NQKV><<<(NQKV * EMBED + 255) / 256, 256, 0, stream>>>(w_qkv, wqkv_t);
  cvt_transpose_f16<EMBED><<<(EMBED * EMBED + 255) / 256, 256, 0, stream>>>(w_proj, wproj_t);

  gemm_kernel<0, 30><<<128 * 30, 256, 0, stream>>>(
      hidden_h, wqkv_t, b_qkv, q_pad, k_pad, v_t, nullptr);

  attn_kernel<<<BATCH * NH * (SEQ / 64), 256, 0, stream>>>(q_pad, k_pad, v_t, attn_out);

  gemm_kernel<1, 10><<<128 * 10, 256, 0, stream>>>(
      attn_out, wproj_t, b_proj, nullptr, nullptr, nullptr, out);
}

// Round 4
// 766.164 us; speedup vs baseline: 1.1433x; 1.0124x over previous
//
#include <hip/hip_runtime.h>

// ---------------- problem constants ----------------
#define BATCH 16
#define SEQ   1024
#define EMBED 1280
#define NH    16
#define HD    80
#define HDP   96           // HD padded to 3*32 for MFMA K-steps
#define NQKV  3840
#define MTOK  (BATCH*SEQ)  // 16384
#define SCALE 0.11180339887498948f
#define LOG2E 1.4426950408889634f

// LDS strides padded to kill bank conflicts (keep 16B alignment for b128 reads)
#define SK_STRIDE 104      // 52 dwords, %32=20 -> 2 lanes/bank (free)
#define SV_STRIDE 72       // 36 dwords, %32=4  -> 2 lanes/bank (free)
#define SP_STRIDE 72

typedef _Float16 half8 __attribute__((ext_vector_type(8)));
typedef _Float16 half4 __attribute__((ext_vector_type(4)));
typedef float floatx4 __attribute__((ext_vector_type(4)));

#define GLD_TO_LDS(gp, lp)                                                        \
  __builtin_amdgcn_global_load_lds(                                               \
      (const __attribute__((address_space(1))) void*)(gp),                        \
      (__attribute__((address_space(3))) void*)(lp), 16, 0, 0)

// 16-lane (DPP-row) all-reduce max on the VALU pipe: xor1, xor2, ~xor4, ~xor8
__device__ __forceinline__ float rowmax16(float x) {
#define DPP_MAX(ctrl)                                                             \
  {                                                                               \
    float y = __int_as_float(                                                     \
        __builtin_amdgcn_update_dpp(0, __float_as_int(x), ctrl, 0xF, 0xF, true)); \
    x = fmaxf(x, y);                                                              \
  }
  DPP_MAX(0xB1);   // quad_perm [1,0,3,2]
  DPP_MAX(0x4E);   // quad_perm [2,3,0,1]
  DPP_MAX(0x141);  // row_half_mirror (values uniform mod 4 -> acts as xor4)
  DPP_MAX(0x140);  // row_mirror      (values uniform mod 8 -> acts as xor8)
#undef DPP_MAX
  return x;
}

// ---------------- converts ----------------
__global__ void cvt_f32_to_f16(const float4* __restrict__ in, _Float16* __restrict__ out, int n4) {
  int i = blockIdx.x * blockDim.x + threadIdx.x;
  if (i < n4) {
    float4 v = in[i];
    half4 h;
    h[0] = (_Float16)v.x; h[1] = (_Float16)v.y; h[2] = (_Float16)v.z; h[3] = (_Float16)v.w;
    *(half4*)(out + (size_t)i * 4) = h;
  }
}

// in [K=1280 x N] fp32 row-major -> out [N x 1280] f16, LDS-tiled (coalesced both sides)
template <int N>
__global__ void cvt_transpose_f16(const float* __restrict__ in, _Float16* __restrict__ out) {
  __shared__ float tile[32][33];
  const int tx = threadIdx.x & 31, ty = threadIdx.x >> 5;  // 256 thr: ty 0..7
  const int k0 = blockIdx.y * 32;
  const int n0 = blockIdx.x * 32;
#pragma unroll
  for (int j = 0; j < 4; ++j)
    tile[ty + 8 * j][tx] = in[(size_t)(k0 + ty + 8 * j) * N + n0 + tx];
  __syncthreads();
#pragma unroll
  for (int j = 0; j < 4; ++j)
    out[(size_t)(n0 + ty + 8 * j) * 1280 + k0 + tx] = (_Float16)tile[tx][ty + 8 * j];
}

// ---------------- GEMM: A[M x 1280] f16 row-major, Bt[N x 1280] f16 row-major ----------------
// MODE 0: QKV epilogue (bias + scatter to q_pad/k_pad/v_t, f16; zeroes d=80..95 pads), NT=30
// MODE 1: proj epilogue (bias + fp32 out [M x 1280]), NT=10
// 1-D grid of 128*NT blocks; XCD-aware swizzle (pid%8 -> contiguous m-strip).
template <int MODE, int NT>
__global__ __launch_bounds__(256, 2)
void gemm_kernel(const _Float16* __restrict__ A, const _Float16* __restrict__ Bt,
                 const float* __restrict__ bias,
                 _Float16* __restrict__ q_pad, _Float16* __restrict__ k_pad,
                 _Float16* __restrict__ v_t, float* __restrict__ outf) {
  __shared__ __align__(16) _Float16 sA[2][128 * 32];
  __shared__ __align__(16) _Float16 sB[2][128 * 32];
  const int K = 1280;
  const int tid = threadIdx.x;
  const int wave = tid >> 6;
  const int lane = tid & 63;
  const int quad = lane >> 4;
  const int r16 = lane & 15;
  const int wm = wave >> 1, wn = wave & 1;

  // swizzle: per-XCD contiguous 16-m-tile strip, traversed in 8m x NT panels (m fastest)
  const int pid = blockIdx.x;
  const int xcd = pid & 7;
  const int local = pid >> 3;               // [0, 16*NT)
  const int panel = local / (8 * NT);       // {0,1}
  const int rr = local - panel * (8 * NT);
  const int pm = rr & 7;
  const int pn = rr >> 3;                   // [0, NT)
  const int m0 = (xcd * 16 + panel * 8 + pm) * 128;
  const int n0 = pn * 128;

  floatx4 acc[4][4] = {};

  const int c_base = wave * 128 + lane;

#define ISSUE(k0, buf)                                                              \
  do {                                                                              \
    _Pragma("unroll")                                                               \
    for (int i = 0; i < 2; ++i) {                                                   \
      int c = c_base + i * 64;                                                      \
      int row = c >> 2, kc = c & 3;                                                 \
      GLD_TO_LDS(A + (size_t)(m0 + row) * K + (k0) + kc * 8,                        \
                 &sA[buf][(wave * 2 + i) * 512]);                                   \
      GLD_TO_LDS(Bt + (size_t)(n0 + row) * K + (k0) + kc * 8,                       \
                 &sB[buf][(wave * 2 + i) * 512]);                                   \
    }                                                                               \
  } while (0)

  ISSUE(0, 0);
  for (int kt = 0; kt < 40; ++kt) {
    __syncthreads();
    if (kt + 1 < 40) ISSUE((kt + 1) * 32, (kt + 1) & 1);
    const _Float16* pA = sA[kt & 1];
    const _Float16* pB = sB[kt & 1];

    half8 af[4], bf[4];
#pragma unroll
    for (int mi = 0; mi < 4; ++mi)
      af[mi] = *(const half8*)(pA + (wm * 64 + mi * 16 + r16) * 32 + quad * 8);
#pragma unroll
    for (int ni = 0; ni < 4; ++ni)
      bf[ni] = *(const half8*)(pB + (wn * 64 + ni * 16 + r16) * 32 + quad * 8);
#pragma unroll
    for (int mi = 0; mi < 4; ++mi)
#pragma unroll
      for (int ni = 0; ni < 4; ++ni)
        acc[mi][ni] = __builtin_amdgcn_mfma_f32_16x16x32_f16(af[mi], bf[ni], acc[mi][ni], 0, 0, 0);
  }

  if (MODE == 1) {
#pragma unroll
    for (int mi = 0; mi < 4; ++mi)
#pragma unroll
      for (int ni = 0; ni < 4; ++ni) {
        int n = n0 + wn * 64 + ni * 16 + r16;
        float bv = bias[n];
#pragma unroll
        for (int r = 0; r < 4; ++r) {
          int m = m0 + wm * 64 + mi * 16 + quad * 4 + r;
          outf[(size_t)m * EMBED + n] = acc[mi][ni][r] + bv;
        }
      }
  } else {
#pragma unroll
    for (int mi = 0; mi < 4; ++mi)
#pragma unroll
      for (int ni = 0; ni < 4; ++ni) {
        int n = n0 + wn * 64 + ni * 16 + r16;
        float bv = bias[n];
        int which = n / 1280;
        int rem = n - which * 1280;
        int h = rem / 80;
        int d = rem - h * 80;
#pragma unroll
        for (int r = 0; r < 4; ++r) {
          int m = m0 + wm * 64 + mi * 16 + quad * 4 + r;
          int b = m >> 10, s = m & 1023;
          int bh = b * NH + h;
          _Float16 val = (_Float16)(acc[mi][ni][r] + bv);
          if (which == 0) {
            q_pad[((size_t)bh * SEQ + s) * HDP + d] = val;
            if (d < 16) q_pad[((size_t)bh * SEQ + s) * HDP + 80 + d] = (_Float16)0.f;
          } else if (which == 1) {
            k_pad[((size_t)bh * SEQ + s) * HDP + d] = val;
            if (d < 16) k_pad[((size_t)bh * SEQ + s) * HDP + 80 + d] = (_Float16)0.f;
          } else {
            v_t[((size_t)bh * HD + d) * SEQ + s] = val;
          }
        }
      }
  }
}

// ---------------- flash attention ----------------
// grid: (BATCH*NH) * (SEQ/128) blocks, 256 thr. wave w owns q-rows [q0+w*32, +32) (mi=0,1).
// sV has 96 d-rows: rows 0..79 = V^T tile, row 80 = ones (row-sum trick), 81..95 = 0.
__global__ __launch_bounds__(256, 2)
void attn_kernel(const _Float16* __restrict__ q_pad, const _Float16* __restrict__ k_pad,
                 const _Float16* __restrict__ v_t, _Float16* __restrict__ attn_out) {
  __shared__ __align__(16) _Float16 sK[64 * SK_STRIDE];      // 13.0 KB
  __shared__ __align__(16) _Float16 sV[96 * SV_STRIDE];      // 13.5 KB
  __shared__ __align__(16) _Float16 sP[4][32 * SP_STRIDE];   // 18.0 KB

  const int tid = threadIdx.x;
  const int wave = tid >> 6, lane = tid & 63, quad = lane >> 4, r16 = lane & 15;
  const int bh = blockIdx.x >> 3;
  const int q0 = (blockIdx.x & 7) * 128;

  // static sV rows 80..95 (ones row + zeros), written once
  if (tid < 128) {
    int row = 80 + (tid >> 3), col = (tid & 7) * 8;
    half8 z;
#pragma unroll
    for (int j = 0; j < 8; ++j) z[j] = (row == 80) ? (_Float16)1.f : (_Float16)0.f;
    *(half8*)(sV + row * SV_STRIDE + col) = z;
  }

  // Q fragments (A-layout), pre-scaled by SCALE*LOG2E so scores are in log2 domain
  half8 qf[2][3];
#pragma unroll
  for (int mi = 0; mi < 2; ++mi) {
    const _Float16* qb = q_pad + ((size_t)bh * SEQ + q0 + wave * 32 + mi * 16 + r16) * HDP;
#pragma unroll
    for (int kq = 0; kq < 3; ++kq) {
      half8 q = *(const half8*)(qb + kq * 32 + quad * 8);
#pragma unroll
      for (int j = 0; j < 8; ++j) q[j] = q[j] * (_Float16)(SCALE * LOG2E);
      qf[mi][kq] = q;
    }
  }

  // per-thread staging slots (computed once)
  int rowK[3], colK[3];
#pragma unroll
  for (int i = 0; i < 3; ++i) {
    int c = tid + i * 256;
    rowK[i] = c / 12; colK[i] = c - rowK[i] * 12;
  }
  const int rowV0 = tid >> 3, colV0 = tid & 7;            // i=0,1: c=tid, tid+256
  const _Float16* kgb = k_pad + ((size_t)bh * SEQ) * HDP;
  const _Float16* vgb = v_t + (size_t)bh * HD * SEQ;

  uint4 pk[3], pv[3];
#define LOADKV(kt)                                                                  \
  do {                                                                              \
    _Pragma("unroll")                                                               \
    for (int i = 0; i < 3; ++i)                                                     \
      pk[i] = *(const uint4*)(kgb + ((size_t)((kt) * 64 + rowK[i])) * HDP + colK[i] * 8); \
    _Pragma("unroll")                                                               \
    for (int i = 0; i < 2; ++i)                                                     \
      pv[i] = *(const uint4*)(vgb + (size_t)(rowV0 + i * 32) * SEQ + (kt) * 64 + colV0 * 8); \
    if (tid < 128)                                                                  \
      pv[2] = *(const uint4*)(vgb + (size_t)(rowV0 + 64) * SEQ + (kt) * 64 + colV0 * 8); \
  } while (0)

  floatx4 o[2][6] = {};
  float mrow[2][4];
#pragma unroll
  for (int mi = 0; mi < 2; ++mi)
#pragma unroll
    for (int r = 0; r < 4; ++r) mrow[mi][r] = -1e30f;

  LOADKV(0);
  for (int kt = 0; kt < 16; ++kt) {
    __syncthreads();  // prev compute done in all waves -> LDS free
#pragma unroll
    for (int i = 0; i < 3; ++i)
      *(uint4*)(sK + rowK[i] * SK_STRIDE + colK[i] * 8) = pk[i];
#pragma unroll
    for (int i = 0; i < 2; ++i)
      *(uint4*)(sV + (rowV0 + i * 32) * SV_STRIDE + colV0 * 8) = pv[i];
    if (tid < 128)
      *(uint4*)(sV + (rowV0 + 64) * SV_STRIDE + colV0 * 8) = pv[2];
    __syncthreads();
    if (kt < 15) LOADKV(kt + 1);  // prefetch flies during compute

    // S = Q K^T : 32 q-rows x 64 keys per wave
    floatx4 sacc[2][4] = {};
#pragma unroll
    for (int ni = 0; ni < 4; ++ni)
#pragma unroll
      for (int kq = 0; kq < 3; ++kq) {
        half8 kf = *(const half8*)(sK + (ni * 16 + r16) * SK_STRIDE + kq * 32 + quad * 8);
#pragma unroll
        for (int mi = 0; mi < 2; ++mi)
          sacc[mi][ni] = __builtin_amdgcn_mfma_f32_16x16x32_f16(qf[mi][kq], kf, sacc[mi][ni], 0, 0, 0);
      }

    // online softmax (log2 domain); sums via ones-row MFMA, max via DPP
#pragma unroll
    for (int mi = 0; mi < 2; ++mi)
#pragma unroll
      for (int r = 0; r < 4; ++r) {
        float mx = fmaxf(fmaxf(sacc[mi][0][r], sacc[mi][1][r]),
                         fmaxf(sacc[mi][2][r], sacc[mi][3][r]));
        mx = rowmax16(mx);
        float mnew = fmaxf(mrow[mi][r], mx);
        float alpha = __builtin_amdgcn_exp2f(mrow[mi][r] - mnew);
        mrow[mi][r] = mnew;
#pragma unroll
        for (int ni = 0; ni < 4; ++ni)
          sacc[mi][ni][r] = __builtin_amdgcn_exp2f(sacc[mi][ni][r] - mnew);
#pragma unroll
        for (int di = 0; di < 6; ++di) o[mi][di][r] *= alpha;
      }

    // P: C-layout -> A-layout via per-wave LDS (same-wave DS ops are in-order)
#pragma unroll
    for (int mi = 0; mi < 2; ++mi)
#pragma unroll
      for (int ni = 0; ni < 4; ++ni)
#pragma unroll
        for (int r = 0; r < 4; ++r)
          sP[wave][(mi * 16 + quad * 4 + r) * SP_STRIDE + ni * 16 + r16] = (_Float16)sacc[mi][ni][r];

#pragma unroll
    for (int kp = 0; kp < 2; ++kp) {
      half8 pf[2];
#pragma unroll
      for (int mi = 0; mi < 2; ++mi)
        pf[mi] = *(const half8*)(&sP[wave][(mi * 16 + r16) * SP_STRIDE + kp * 32 + quad * 8]);
#pragma unroll
      for (int di = 0; di < 6; ++di) {
        half8 vf = *(const half8*)(sV + (di * 16 + r16) * SV_STRIDE + kp * 32 + quad * 8);
#pragma unroll
        for (int mi = 0; mi < 2; ++mi)
          o[mi][di] = __builtin_amdgcn_mfma_f32_16x16x32_f16(pf[mi], vf, o[mi][di], 0, 0, 0);
      }
    }
  }

  // epilogue: l = o[mi][5] at col 80 (r16==0 lane of each 16-group); attn_out[b,s,h*80+d] f16
  const int b = bh >> 4, h = bh & 15;
#pragma unroll
  for (int mi = 0; mi < 2; ++mi)
#pragma unroll
    for (int r = 0; r < 4; ++r) {
      float l = __shfl(o[mi][5][r], lane & 48);
      float inv = 1.0f / l;
      int tok = b * SEQ + q0 + wave * 32 + mi * 16 + quad * 4 + r;
#pragma unroll
      for (int di = 0; di < 5; ++di) {
        int e = h * HD + di * 16 + r16;
        attn_out[(size_t)tok * EMBED + e] = (_Float16)(o[mi][di][r] * inv);
      }
    }
}

// ---------------- launch ----------------
extern "C" void kernel_launch(void* const* d_in, const int* in_sizes, int n_in,
                              void* d_out, int out_size, void* d_ws, size_t ws_size,
                              hipStream_t stream) {
  const float* hidden = (const float*)d_in[0];
  const float* w_qkv  = (const float*)d_in[1];
  const float* b_qkv  = (const float*)d_in[2];
  const float* w_proj = (const float*)d_in[3];
  const float* b_proj = (const float*)d_in[4];
  float* out = (float*)d_out;

  char* ws = (char*)d_ws;
  size_t off = 0;
  _Float16* hidden_h = (_Float16*)(ws + off); off += (size_t)MTOK * EMBED * 2;
  _Float16* wqkv_t   = (_Float16*)(ws + off); off += (size_t)NQKV * EMBED * 2;
  _Float16* wproj_t  = (_Float16*)(ws + off); off += (size_t)EMBED * EMBED * 2;
  _Float16* q_pad    = (_Float16*)(ws + off); off += (size_t)BATCH * NH * SEQ * HDP * 2;
  _Float16* k_pad    = (_Float16*)(ws + off); off += (size_t)BATCH * NH * SEQ * HDP * 2;
  _Float16* v_t      = (_Float16*)(ws + off); off += (size_t)BATCH * NH * HD * SEQ * 2;
  _Float16* attn_out = hidden_h;  // alias: hidden_h consumed before attention writes

  {
    int n4 = MTOK * EMBED / 4;
    cvt_f32_to_f16<<<(n4 + 255) / 256, 256, 0, stream>>>((const float4*)hidden, hidden_h, n4);
  }
  cvt_transpose_f16<NQKV><<<dim3(NQKV / 32, 1280 / 32), 256, 0, stream>>>(w_qkv, wqkv_t);
  cvt_transpose_f16<EMBED><<<dim3(EMBED / 32, 1280 / 32), 256, 0, stream>>>(w_proj, wproj_t);

  gemm_kernel<0, 30><<<128 * 30, 256, 0, stream>>>(
      hidden_h, wqkv_t, b_qkv, q_pad, k_pad, v_t, nullptr);

  attn_kernel<<<BATCH * NH * (SEQ / 128), 256, 0, stream>>>(q_pad, k_pad, v_t, attn_out);

  gemm_kernel<1, 10><<<128 * 10, 256, 0, stream>>>(
      attn_out, wproj_t, b_proj, nullptr, nullptr, nullptr, out);
}

// Round 5
// 648.821 us; speedup vs baseline: 1.3500x; 1.1809x over previous
//
#include <hip/hip_runtime.h>

// ---------------- problem constants ----------------
#define BATCH 16
#define SEQ   1024
#define EMBED 1280
#define NH    16
#define HD    80
#define HDP   96           // HD padded to 3*32 for MFMA K-steps
#define NQKV  3840
#define MTOK  (BATCH*SEQ)  // 16384
#define SCALE 0.11180339887498948f
#define LOG2E 1.4426950408889634f

// LDS strides padded to kill bank conflicts (keep 16B alignment for b128 reads)
#define SK_STRIDE 104      // 52 dwords
#define SV_STRIDE 72       // 36 dwords
#define SP_STRIDE 72

typedef _Float16 half8 __attribute__((ext_vector_type(8)));
typedef _Float16 half4 __attribute__((ext_vector_type(4)));
typedef float floatx4 __attribute__((ext_vector_type(4)));

#define GLD_TO_LDS(gp, lp)                                                        \
  __builtin_amdgcn_global_load_lds(                                               \
      (const __attribute__((address_space(1))) void*)(gp),                        \
      (__attribute__((address_space(3))) void*)(lp), 16, 0, 0)

// 16-lane all-reduce max on the VALU pipe (DPP)
__device__ __forceinline__ float rowmax16(float x) {
#define DPP_MAX(ctrl)                                                             \
  {                                                                               \
    float y = __int_as_float(                                                     \
        __builtin_amdgcn_update_dpp(0, __float_as_int(x), ctrl, 0xF, 0xF, true)); \
    x = fmaxf(x, y);                                                              \
  }
  DPP_MAX(0xB1);   // quad_perm [1,0,3,2]  (xor1)
  DPP_MAX(0x4E);   // quad_perm [2,3,0,1]  (xor2)
  DPP_MAX(0x141);  // row_half_mirror      (xor4 after uniform mod 4)
  DPP_MAX(0x140);  // row_mirror           (xor8 after uniform mod 8)
#undef DPP_MAX
  return x;
}

// ---------------- converts ----------------
__global__ void cvt_f32_to_f16(const float4* __restrict__ in, _Float16* __restrict__ out, int n4) {
  int i = blockIdx.x * blockDim.x + threadIdx.x;
  if (i < n4) {
    float4 v = in[i];
    half4 h;
    h[0] = (_Float16)v.x; h[1] = (_Float16)v.y; h[2] = (_Float16)v.z; h[3] = (_Float16)v.w;
    *(half4*)(out + (size_t)i * 4) = h;
  }
}

// in [K=1280 x N] fp32 row-major -> out [N x 1280] f16, LDS-tiled (coalesced both sides)
template <int N>
__global__ void cvt_transpose_f16(const float* __restrict__ in, _Float16* __restrict__ out) {
  __shared__ float tile[32][33];
  const int tx = threadIdx.x & 31, ty = threadIdx.x >> 5;  // 256 thr: ty 0..7
  const int k0 = blockIdx.y * 32;
  const int n0 = blockIdx.x * 32;
#pragma unroll
  for (int j = 0; j < 4; ++j)
    tile[ty + 8 * j][tx] = in[(size_t)(k0 + ty + 8 * j) * N + n0 + tx];
  __syncthreads();
#pragma unroll
  for (int j = 0; j < 4; ++j)
    out[(size_t)(n0 + ty + 8 * j) * 1280 + k0 + tx] = (_Float16)tile[tx][ty + 8 * j];
}

// ---------------- GEMM: A[M x 1280] f16 row-major, Bt[N x 1280] f16 row-major ----------------
template <int MODE, int NT>
__global__ __launch_bounds__(256, 2)
void gemm_kernel(const _Float16* __restrict__ A, const _Float16* __restrict__ Bt,
                 const float* __restrict__ bias,
                 _Float16* __restrict__ q_pad, _Float16* __restrict__ k_pad,
                 _Float16* __restrict__ v_t, float* __restrict__ outf) {
  __shared__ __align__(16) _Float16 sA[2][128 * 32];
  __shared__ __align__(16) _Float16 sB[2][128 * 32];
  const int K = 1280;
  const int tid = threadIdx.x;
  const int wave = tid >> 6;
  const int lane = tid & 63;
  const int quad = lane >> 4;
  const int r16 = lane & 15;
  const int wm = wave >> 1, wn = wave & 1;

  // swizzle: per-XCD contiguous 16-m-tile strip, traversed in 8m x NT panels (m fastest)
  const int pid = blockIdx.x;
  const int xcd = pid & 7;
  const int local = pid >> 3;
  const int panel = local / (8 * NT);
  const int rr = local - panel * (8 * NT);
  const int pm = rr & 7;
  const int pn = rr >> 3;
  const int m0 = (xcd * 16 + panel * 8 + pm) * 128;
  const int n0 = pn * 128;

  floatx4 acc[4][4] = {};

  const int c_base = wave * 128 + lane;

#define ISSUE(k0, buf)                                                              \
  do {                                                                              \
    _Pragma("unroll")                                                               \
    for (int i = 0; i < 2; ++i) {                                                   \
      int c = c_base + i * 64;                                                      \
      int row = c >> 2, kc = c & 3;                                                 \
      GLD_TO_LDS(A + (size_t)(m0 + row) * K + (k0) + kc * 8,                        \
                 &sA[buf][(wave * 2 + i) * 512]);                                   \
      GLD_TO_LDS(Bt + (size_t)(n0 + row) * K + (k0) + kc * 8,                       \
                 &sB[buf][(wave * 2 + i) * 512]);                                   \
    }                                                                               \
  } while (0)

  ISSUE(0, 0);
  for (int kt = 0; kt < 40; ++kt) {
    __syncthreads();
    if (kt + 1 < 40) ISSUE((kt + 1) * 32, (kt + 1) & 1);
    const _Float16* pA = sA[kt & 1];
    const _Float16* pB = sB[kt & 1];

    half8 af[4], bf[4];
#pragma unroll
    for (int mi = 0; mi < 4; ++mi)
      af[mi] = *(const half8*)(pA + (wm * 64 + mi * 16 + r16) * 32 + quad * 8);
#pragma unroll
    for (int ni = 0; ni < 4; ++ni)
      bf[ni] = *(const half8*)(pB + (wn * 64 + ni * 16 + r16) * 32 + quad * 8);
#pragma unroll
    for (int mi = 0; mi < 4; ++mi)
#pragma unroll
      for (int ni = 0; ni < 4; ++ni)
        acc[mi][ni] = __builtin_amdgcn_mfma_f32_16x16x32_f16(af[mi], bf[ni], acc[mi][ni], 0, 0, 0);
  }

  if (MODE == 1) {
#pragma unroll
    for (int mi = 0; mi < 4; ++mi)
#pragma unroll
      for (int ni = 0; ni < 4; ++ni) {
        int n = n0 + wn * 64 + ni * 16 + r16;
        float bv = bias[n];
#pragma unroll
        for (int r = 0; r < 4; ++r) {
          int m = m0 + wm * 64 + mi * 16 + quad * 4 + r;
          outf[(size_t)m * EMBED + n] = acc[mi][ni][r] + bv;
        }
      }
  } else {
#pragma unroll
    for (int mi = 0; mi < 4; ++mi)
#pragma unroll
      for (int ni = 0; ni < 4; ++ni) {
        int n = n0 + wn * 64 + ni * 16 + r16;
        float bv = bias[n];
        int which = n / 1280;
        int rem = n - which * 1280;
        int h = rem / 80;
        int d = rem - h * 80;
#pragma unroll
        for (int r = 0; r < 4; ++r) {
          int m = m0 + wm * 64 + mi * 16 + quad * 4 + r;
          int b = m >> 10, s = m & 1023;
          int bh = b * NH + h;
          _Float16 val = (_Float16)(acc[mi][ni][r] + bv);
          if (which == 0) {
            q_pad[((size_t)bh * SEQ + s) * HDP + d] = val;
            if (d < 16) q_pad[((size_t)bh * SEQ + s) * HDP + 80 + d] = (_Float16)0.f;
          } else if (which == 1) {
            k_pad[((size_t)bh * SEQ + s) * HDP + d] = val;
            if (d < 16) k_pad[((size_t)bh * SEQ + s) * HDP + 80 + d] = (_Float16)0.f;
          } else {
            v_t[((size_t)bh * HD + d) * SEQ + s] = val;
          }
        }
      }
  }
}

// ---------------- flash attention ----------------
// grid: (BATCH*NH) * (SEQ/128) blocks, 256 thr. wave w owns q-rows [q0+w*32, +32) (mi=0,1).
// sV has 96 d-rows: rows 0..79 = V^T tile, row 80 = ones (row-sum trick), 81..95 = 0.
// Staging: load -> immediate LDS store (transient regs only — NO cross-iter prefetch,
// R4's persistent prefetch spilled to scratch: 700 MB of HBM writes).
__global__ __launch_bounds__(256, 2)
void attn_kernel(const _Float16* __restrict__ q_pad, const _Float16* __restrict__ k_pad,
                 const _Float16* __restrict__ v_t, _Float16* __restrict__ attn_out) {
  __shared__ __align__(16) _Float16 sK[64 * SK_STRIDE];      // 13.0 KB
  __shared__ __align__(16) _Float16 sV[96 * SV_STRIDE];      // 13.5 KB
  __shared__ __align__(16) _Float16 sP[4][16 * SP_STRIDE];   //  9.0 KB (reused mi=0 then mi=1)

  const int tid = threadIdx.x;
  const int wave = tid >> 6, lane = tid & 63, quad = lane >> 4, r16 = lane & 15;
  const int bh = blockIdx.x >> 3;
  const int q0 = (blockIdx.x & 7) * 128;

  // static sV rows 80..95 (ones row + zeros), written once; never overwritten in-loop
  if (tid < 128) {
    int row = 80 + (tid >> 3), col = (tid & 7) * 8;
    half8 z;
#pragma unroll
    for (int j = 0; j < 8; ++j) z[j] = (row == 80) ? (_Float16)1.f : (_Float16)0.f;
    *(half8*)(sV + row * SV_STRIDE + col) = z;
  }

  // Q fragments (A-layout), pre-scaled by SCALE*LOG2E (log2-domain softmax)
  half8 qf[2][3];
#pragma unroll
  for (int mi = 0; mi < 2; ++mi) {
    const _Float16* qb = q_pad + ((size_t)bh * SEQ + q0 + wave * 32 + mi * 16 + r16) * HDP;
#pragma unroll
    for (int kq = 0; kq < 3; ++kq) {
      half8 q = *(const half8*)(qb + kq * 32 + quad * 8);
#pragma unroll
      for (int j = 0; j < 8; ++j) q[j] = q[j] * (_Float16)(SCALE * LOG2E);
      qf[mi][kq] = q;
    }
  }

  // per-thread staging slots
  int rowK[3], colK[3];
#pragma unroll
  for (int i = 0; i < 3; ++i) {
    int c = tid + i * 256;
    rowK[i] = c / 12; colK[i] = c - rowK[i] * 12;
  }
  const int rowV0 = tid >> 3, colV0 = tid & 7;
  const _Float16* kgb = k_pad + ((size_t)bh * SEQ) * HDP;
  const _Float16* vgb = v_t + (size_t)bh * HD * SEQ;

  floatx4 o[2][6] = {};
  float mrow[2][4];
#pragma unroll
  for (int mi = 0; mi < 2; ++mi)
#pragma unroll
    for (int r = 0; r < 4; ++r) mrow[mi][r] = -1e30f;

  for (int kt = 0; kt < 16; ++kt) {
    __syncthreads();  // prev compute done in all waves -> LDS free
    {
      // load -> store immediately (transient regs; compiler overlaps via vmcnt)
      uint4 tk0 = *(const uint4*)(kgb + ((size_t)(kt * 64 + rowK[0])) * HDP + colK[0] * 8);
      uint4 tk1 = *(const uint4*)(kgb + ((size_t)(kt * 64 + rowK[1])) * HDP + colK[1] * 8);
      uint4 tk2 = *(const uint4*)(kgb + ((size_t)(kt * 64 + rowK[2])) * HDP + colK[2] * 8);
      uint4 tv0 = *(const uint4*)(vgb + (size_t)(rowV0) * SEQ + kt * 64 + colV0 * 8);
      uint4 tv1 = *(const uint4*)(vgb + (size_t)(rowV0 + 32) * SEQ + kt * 64 + colV0 * 8);
      uint4 tv2;
      if (tid < 128)
        tv2 = *(const uint4*)(vgb + (size_t)(rowV0 + 64) * SEQ + kt * 64 + colV0 * 8);
      *(uint4*)(sK + rowK[0] * SK_STRIDE + colK[0] * 8) = tk0;
      *(uint4*)(sK + rowK[1] * SK_STRIDE + colK[1] * 8) = tk1;
      *(uint4*)(sK + rowK[2] * SK_STRIDE + colK[2] * 8) = tk2;
      *(uint4*)(sV + (rowV0) * SV_STRIDE + colV0 * 8) = tv0;
      *(uint4*)(sV + (rowV0 + 32) * SV_STRIDE + colV0 * 8) = tv1;
      if (tid < 128)
        *(uint4*)(sV + (rowV0 + 64) * SV_STRIDE + colV0 * 8) = tv2;
    }
    __syncthreads();

    // S = Q K^T : 32 q-rows x 64 keys per wave
    floatx4 sacc[2][4] = {};
#pragma unroll
    for (int ni = 0; ni < 4; ++ni)
#pragma unroll
      for (int kq = 0; kq < 3; ++kq) {
        half8 kf = *(const half8*)(sK + (ni * 16 + r16) * SK_STRIDE + kq * 32 + quad * 8);
#pragma unroll
        for (int mi = 0; mi < 2; ++mi)
          sacc[mi][ni] = __builtin_amdgcn_mfma_f32_16x16x32_f16(qf[mi][kq], kf, sacc[mi][ni], 0, 0, 0);
      }

    // online softmax (log2 domain); sums via ones-row MFMA, max via DPP
#pragma unroll
    for (int mi = 0; mi < 2; ++mi)
#pragma unroll
      for (int r = 0; r < 4; ++r) {
        float mx = fmaxf(fmaxf(sacc[mi][0][r], sacc[mi][1][r]),
                         fmaxf(sacc[mi][2][r], sacc[mi][3][r]));
        mx = rowmax16(mx);
        float mnew = fmaxf(mrow[mi][r], mx);
        float alpha = __builtin_amdgcn_exp2f(mrow[mi][r] - mnew);
        mrow[mi][r] = mnew;
#pragma unroll
        for (int ni = 0; ni < 4; ++ni)
          sacc[mi][ni][r] = __builtin_amdgcn_exp2f(sacc[mi][ni][r] - mnew);
#pragma unroll
        for (int di = 0; di < 6; ++di) o[mi][di][r] *= alpha;
      }

    // P: C-layout -> A-layout via per-wave LDS buffer, reused across mi
    // (same-wave DS ops complete in order -> no barrier needed between mi phases)
#pragma unroll
    for (int mi = 0; mi < 2; ++mi) {
#pragma unroll
      for (int ni = 0; ni < 4; ++ni)
#pragma unroll
        for (int r = 0; r < 4; ++r)
          sP[wave][(quad * 4 + r) * SP_STRIDE + ni * 16 + r16] = (_Float16)sacc[mi][ni][r];
#pragma unroll
      for (int kp = 0; kp < 2; ++kp) {
        half8 pf = *(const half8*)(&sP[wave][r16 * SP_STRIDE + kp * 32 + quad * 8]);
#pragma unroll
        for (int di = 0; di < 6; ++di) {
          half8 vf = *(const half8*)(sV + (di * 16 + r16) * SV_STRIDE + kp * 32 + quad * 8);
          o[mi][di] = __builtin_amdgcn_mfma_f32_16x16x32_f16(pf, vf, o[mi][di], 0, 0, 0);
        }
      }
    }
  }

  // epilogue: l = o[mi][5] col 80 lives in r16==0 lane of each 16-group
  const int b = bh >> 4, h = bh & 15;
#pragma unroll
  for (int mi = 0; mi < 2; ++mi)
#pragma unroll
    for (int r = 0; r < 4; ++r) {
      float l = __shfl(o[mi][5][r], lane & 48);
      float inv = 1.0f / l;
      int tok = b * SEQ + q0 + wave * 32 + mi * 16 + quad * 4 + r;
#pragma unroll
      for (int di = 0; di < 5; ++di) {
        int e = h * HD + di * 16 + r16;
        attn_out[(size_t)tok * EMBED + e] = (_Float16)(o[mi][di][r] * inv);
      }
    }
}

// ---------------- launch ----------------
extern "C" void kernel_launch(void* const* d_in, const int* in_sizes, int n_in,
                              void* d_out, int out_size, void* d_ws, size_t ws_size,
                              hipStream_t stream) {
  const float* hidden = (const float*)d_in[0];
  const float* w_qkv  = (const float*)d_in[1];
  const float* b_qkv  = (const float*)d_in[2];
  const float* w_proj = (const float*)d_in[3];
  const float* b_proj = (const float*)d_in[4];
  float* out = (float*)d_out;

  char* ws = (char*)d_ws;
  size_t off = 0;
  _Float16* hidden_h = (_Float16*)(ws + off); off += (size_t)MTOK * EMBED * 2;
  _Float16* wqkv_t   = (_Float16*)(ws + off); off += (size_t)NQKV * EMBED * 2;
  _Float16* wproj_t  = (_Float16*)(ws + off); off += (size_t)EMBED * EMBED * 2;
  _Float16* q_pad    = (_Float16*)(ws + off); off += (size_t)BATCH * NH * SEQ * HDP * 2;
  _Float16* k_pad    = (_Float16*)(ws + off); off += (size_t)BATCH * NH * SEQ * HDP * 2;
  _Float16* v_t      = (_Float16*)(ws + off); off += (size_t)BATCH * NH * HD * SEQ * 2;
  _Float16* attn_out = hidden_h;  // alias: hidden_h consumed before attention writes

  {
    int n4 = MTOK * EMBED / 4;
    cvt_f32_to_f16<<<(n4 + 255) / 256, 256, 0, stream>>>((const float4*)hidden, hidden_h, n4);
  }
  cvt_transpose_f16<NQKV><<<dim3(NQKV / 32, 1280 / 32), 256, 0, stream>>>(w_qkv, wqkv_t);
  cvt_transpose_f16<EMBED><<<dim3(EMBED / 32, 1280 / 32), 256, 0, stream>>>(w_proj, wproj_t);

  gemm_kernel<0, 30><<<128 * 30, 256, 0, stream>>>(
      hidden_h, wqkv_t, b_qkv, q_pad, k_pad, v_t, nullptr);

  attn_kernel<<<BATCH * NH * (SEQ / 128), 256, 0, stream>>>(q_pad, k_pad, v_t, attn_out);

  gemm_kernel<1, 10><<<128 * 10, 256, 0, stream>>>(
      attn_out, wproj_t, b_proj, nullptr, nullptr, nullptr, out);
}